// Round 17
// baseline (364.763 us; speedup 1.0000x reference)
//
#include <hip/hip_runtime.h>
#include <hip/hip_bf16.h>
#include <math.h>

// TopK router: logits = x @ gate_w^T, softmax, top-2, renormalize.
// M=32768 tokens, K=4096, E=64 experts.
// Outputs (concat, harness reads whole buffer as float32):
//   d_out[0 .. 2M)  : top-2 weights (descending)
//   d_out[2M .. 4M) : top-2 expert indices, stored as float values
//
// R17 = DIAGNOSTIC: exactly R16's structure, but the chunk loop runs TWO
// full passes (acc 2x, scaled by 0.5f at dump; ~1e-6 noise << TAU refine).
// Purpose: dispatch ~460us > the harness's 320us fill kernels, so the main
// kernel finally enters rocprof's top-5 and we see MfmaUtil / VALUBusy /
// Occupancy / FETCH / bank conflicts for the plateau structure. Six
// structural variants (R5,R13,R14,R15,R16) all hit 233-247us; the next
// move is chosen by these counters, not another blind theory.

typedef __attribute__((ext_vector_type(8))) short short8;
typedef __attribute__((ext_vector_type(4))) float f32x4;

#define TPB 32
#define NCH 32      // K/128 chunks
#define NREP 2      // diagnostic repeat
#define TAU 1e-4f
#define LROW 68

__device__ __forceinline__ void cvt8(const f32x4* v, short8* hi, short8* lo) {
    const float* f = reinterpret_cast<const float*>(v);
#pragma unroll
    for (int j = 0; j < 8; ++j) {
        __hip_bfloat16 h = __float2bfloat16(f[j]);
        float r = f[j] - __bfloat162float(h);
        __hip_bfloat16 l = __float2bfloat16(r);
        (*hi)[j] = (short)*reinterpret_cast<unsigned short*>(&h);
        (*lo)[j] = (short)*reinterpret_cast<unsigned short*>(&l);
    }
}

// Pack gw into MFMA-fragment order: entry (nt*8192 + w*64 + ln) = 8 bf16 of
// row nt*16+(ln&15), k = w*32 + (ln>>4)*8.
__global__ void prep_b(const float* __restrict__ gw,
                       short8* __restrict__ bh, short8* __restrict__ bl) {
    const int tid = blockIdx.x * 256 + threadIdx.x;
    const int ln  = tid & 63;
    const int w   = (tid >> 6) & 127;
    const int nt  = tid >> 13;
    const int row = nt * 16 + (ln & 15);
    const int k   = w * 32 + ((ln >> 4) << 3);
    f32x4 v[2];
    v[0] = *reinterpret_cast<const f32x4*>(gw + (long)row * 4096 + k);
    v[1] = *reinterpret_cast<const f32x4*>(gw + (long)row * 4096 + k + 4);
    short8 h, l;
    cvt8(v, &h, &l);
    bh[tid] = h;
    bl[tid] = l;
}

__device__ __forceinline__ void gload16(const void* g, void* l) {
    __builtin_amdgcn_global_load_lds(
        (const __attribute__((address_space(1))) void*)g,
        (__attribute__((address_space(3))) void*)l, 16, 0, 0);
}

// A LDS: [32 rows][512B] per buffer; buf0 @0, buf1 @16384.
#define STAGE(C, BUF) do {                                                    \
    char* aB = AB + (BUF) * 16384;                                            \
    _Pragma("unroll")                                                         \
    for (int i = 0; i < 4; ++i)                                               \
        gload16(srcA[i] + (long)(C) * 512, aB + (wv * 4 + i) * 1024 + ln * 16); \
} while (0)

__global__ __launch_bounds__(256, 4)
void router_fused(const float* __restrict__ x,
                  const short8* __restrict__ bhp,
                  const short8* __restrict__ blp,
                  const float* __restrict__ gw,
                  float* __restrict__ out,
                  int M, int K) {
    __shared__ __align__(16) char AB[32768];
    __shared__ int flags[TPB];
    __shared__ double Ld4[4][64];

    const int t  = threadIdx.x;
    const int wv = t >> 6;
    const int ln = t & 63;
    const int fr = ln & 15;
    const int q  = ln >> 4;
    const int mm = wv >> 1;                 // m-tile (16 tokens)
    const int nn = wv & 1;                  // n-half (32 experts)
    const long tok0 = (long)blockIdx.x * TPB;
    const int phase = blockIdx.x & (NCH - 1);   // K-phase stagger

    // A staging sources: instr i covers rows 2*(wv*4+i)+(ln>>5); slot
    // (ln&31) pre-swizzled by row&7 within each 8-slot (128B) octet.
    const char* srcA[4];
#pragma unroll
    for (int i = 0; i < 4; ++i) {
        const int row  = 2 * (wv * 4 + i) + (ln >> 5);
        const int slot = (ln & 31);
        const int swz  = (slot & ~7) | ((slot & 7) ^ (row & 7));
        srcA[i] = (const char*)x + (tok0 + row) * (long)K * 4 + swz * 16;
    }

    f32x4 acc[2];
    acc[0] = (f32x4){0.f, 0.f, 0.f, 0.f};
    acc[1] = (f32x4){0.f, 0.f, 0.f, 0.f};

    STAGE(phase, 0);
    STAGE((phase + 1) & (NCH - 1), 1);

    const int R = mm * 16 + fr;             // A row this lane reads
    const int rk = R & 7;                   // swizzle key

    const int TOT = NREP * NCH;             // 64 iterations (2 passes)
    for (int j = 0; j < TOT; ++j) {
        const int c   = (phase + j) & (NCH - 1);
        const int buf = j & 1;
        if (j + 1 < TOT) asm volatile("s_waitcnt vmcnt(4)" ::: "memory");
        else             asm volatile("s_waitcnt vmcnt(0)" ::: "memory");
        __builtin_amdgcn_s_barrier();
        asm volatile("" ::: "memory");
        __builtin_amdgcn_sched_barrier(0);

        // ---- compute chunk c: 4 windows of k=32 ----
        {
            const char* aB = AB + buf * 16384 + R * 512;
#pragma unroll
            for (int w = 0; w < 4; ++w) {
                f32x4 av[2];
                av[0] = *(const f32x4*)(aB + (w * 8 + ((q * 2 + 0) ^ rk)) * 16);
                av[1] = *(const f32x4*)(aB + (w * 8 + ((q * 2 + 1) ^ rk)) * 16);
                short8 ah, al;
                cvt8(av, &ah, &al);
                const int widx = c * 4 + w;
#pragma unroll
                for (int ntl = 0; ntl < 2; ++ntl) {
                    const int nt = 2 * nn + ntl;
                    short8 bhv = bhp[nt * 8192 + widx * 64 + ln];
                    short8 blv = blp[nt * 8192 + widx * 64 + ln];
                    acc[ntl] = __builtin_amdgcn_mfma_f32_16x16x32_bf16(ah, bhv, acc[ntl], 0, 0, 0);
                    acc[ntl] = __builtin_amdgcn_mfma_f32_16x16x32_bf16(ah, blv, acc[ntl], 0, 0, 0);
                    acc[ntl] = __builtin_amdgcn_mfma_f32_16x16x32_bf16(al, bhv, acc[ntl], 0, 0, 0);
                    acc[ntl] = __builtin_amdgcn_mfma_f32_16x16x32_bf16(al, blv, acc[ntl], 0, 0, 0);
                }
            }
        }

        __builtin_amdgcn_sched_barrier(0);
        asm volatile("" ::: "memory");
        __builtin_amdgcn_s_barrier();       // all waves done reading buf
        asm volatile("" ::: "memory");
        if (j + 2 < TOT) STAGE((phase + j + 2) & (NCH - 1), buf);
        __builtin_amdgcn_sched_barrier(0);
    }

    // ---- epilogue: dump logits scaled by 1/NREP (C/D layout) ----
    __syncthreads();
    float* Ls = (float*)AB;                 // loop done; alias A buffers
#pragma unroll
    for (int ntl = 0; ntl < 2; ++ntl)
#pragma unroll
        for (int r = 0; r < 4; ++r)
            Ls[(mm * 16 + q * 4 + r) * LROW + (2 * nn + ntl) * 16 + fr] =
                acc[ntl][r] * 0.5f;
    __syncthreads();

    if (t < TPB) {
        const float* row = Ls + (long)t * LROW;
        float m1 = -INFINITY, m2 = -INFINITY, m3 = -INFINITY;
        int i1 = 0, i2 = 0;
#pragma unroll 8
        for (int e = 0; e < 64; ++e) {
            const float v = row[e];
            if (v > m1)      { m3 = m2; m2 = m1; i2 = i1; m1 = v; i1 = e; }
            else if (v > m2) { m3 = m2; m2 = v; i2 = e; }
            else if (v > m3) { m3 = v; }
        }
        const float e2 = expf(m2 - m1);
        const float s  = 1.0f + e2;

        const long g = tok0 + t;
        out[2 * g + 0] = 1.0f / s;
        out[2 * g + 1] = e2 / s;
        float* oi = out + 2 * (long)M;
        oi[2 * g + 0] = (float)i1;
        oi[2 * g + 1] = (float)i2;

        flags[t] = ((m1 - m2) < TAU) | ((m2 - m3) < TAU);
    }
    __syncthreads();

    // ---- fp64 refine, 256 threads cooperate (wave=K-quarter, lane=expert) ----
    for (int tk = 0; tk < TPB; ++tk) {
        if (flags[tk]) {
            const float* xr = x + (tok0 + tk) * (long)K + wv * 1024;
            const float* gr = gw + (long)ln * (long)K + wv * 1024;
            double s0 = 0.0, s1 = 0.0, s2 = 0.0, s3 = 0.0;
            for (int k = 0; k < 1024; k += 4) {
                const f32x4 a = *reinterpret_cast<const f32x4*>(xr + k);
                const f32x4 b = *reinterpret_cast<const f32x4*>(gr + k);
                s0 = fma((double)a.x, (double)b.x, s0);
                s1 = fma((double)a.y, (double)b.y, s1);
                s2 = fma((double)a.z, (double)b.z, s2);
                s3 = fma((double)a.w, (double)b.w, s3);
            }
            Ld4[wv][ln] = (s0 + s1) + (s2 + s3);
            __syncthreads();
            if (t == 0) {
                double m1 = -INFINITY, m2 = -INFINITY;
                int i1 = 0, i2 = 0;
                for (int e = 0; e < 64; ++e) {
                    const double v = Ld4[0][e] + Ld4[1][e] + Ld4[2][e] + Ld4[3][e];
                    if (v > m1)      { m2 = m1; i2 = i1; m1 = v; i1 = e; }
                    else if (v > m2) { m2 = v; i2 = e; }
                }
                const double e2 = exp(m2 - m1);
                const double s  = 1.0 + e2;
                const long g = tok0 + tk;
                out[2 * g + 0] = (float)(1.0 / s);
                out[2 * g + 1] = (float)(e2 / s);
                float* oi = out + 2 * (long)M;
                oi[2 * g + 0] = (float)i1;
                oi[2 * g + 1] = (float)i2;
            }
            __syncthreads();
        }
    }
}

extern "C" void kernel_launch(void* const* d_in, const int* in_sizes, int n_in,
                              void* d_out, int out_size, void* d_ws, size_t ws_size,
                              hipStream_t stream) {
    const float* x  = (const float*)d_in[0];
    const float* gw = (const float*)d_in[1];
    float* out = (float*)d_out;

    const int K = 4096;
    const int M = in_sizes[0] / K;          // 32768 tokens
    const int nblocks = M / TPB;            // 1024

    short8* bh = (short8*)d_ws;             // 1 MB packed B
    short8* bl = bh + 32768;

    prep_b<<<128, 256, 0, stream>>>(gw, bh, bl);
    router_fused<<<nblocks, 256, 0, stream>>>(x, bh, bl, gw, out, M, K);
}

// Round 18
// 206.072 us; speedup vs baseline: 1.7701x; 1.7701x over previous
//
#include <hip/hip_runtime.h>
#include <hip/hip_bf16.h>
#include <math.h>

// TopK router: logits = x @ gate_w^T, softmax, top-2, renormalize.
// M=32768 tokens, K=4096, E=64 experts.
// Outputs (concat, harness reads whole buffer as float32):
//   d_out[0 .. 2M)  : top-2 weights (descending)
//   d_out[2M .. 4M) : top-2 expert indices, stored as float values
//
// R18: R17's counters showed additive phases: MFMA 27 + cvt 30 + x-HBM 65
// + B-L2 60 (2GB! register B loads, 2x duplicated) + LDS 30 ~= the 233us
// plateau. Fixes: (1) B staged to LDS via DMA once per block per chunk
// (L2 B-traffic 2GB -> 512MB, latency moved into the DMA queue);
// (2) wave = 1 m-tile x ALL 64 experts (T=64 tok/block): zero redundant
// cvt work, MFMA:cvt 8:1, 64 MFMA between barriers; (3) k=64 chunks,
// A 16KB + B 16KB double-buffered (64KB LDS, 2 blocks/CU), counted
// vmcnt(8), XOR-swizzled A (proven R15-17), K-phase stagger (R16),
// top-3 + TAU=1e-4 + parallel fp64 refine epilogue (proven R5+).

typedef __attribute__((ext_vector_type(8))) short short8;
typedef __attribute__((ext_vector_type(4))) float f32x4;

#define TPB 64      // tokens per block
#define NCH 64      // K/64 chunks
#define TAU 1e-4f
#define LROW 68

__device__ __forceinline__ void cvt8(const f32x4* v, short8* hi, short8* lo) {
    const float* f = reinterpret_cast<const float*>(v);
#pragma unroll
    for (int j = 0; j < 8; ++j) {
        __hip_bfloat16 h = __float2bfloat16(f[j]);
        float r = f[j] - __bfloat162float(h);
        __hip_bfloat16 l = __float2bfloat16(r);
        (*hi)[j] = (short)*reinterpret_cast<unsigned short*>(&h);
        (*lo)[j] = (short)*reinterpret_cast<unsigned short*>(&l);
    }
}

// Pack gw into MFMA-fragment order: entry (nt*8192 + w*64 + ln) = 8 bf16 of
// row nt*16+(ln&15), k = w*32 + (ln>>4)*8.
__global__ void prep_b(const float* __restrict__ gw,
                       short8* __restrict__ bh, short8* __restrict__ bl) {
    const int tid = blockIdx.x * 256 + threadIdx.x;
    const int ln  = tid & 63;
    const int w   = (tid >> 6) & 127;
    const int nt  = tid >> 13;
    const int row = nt * 16 + (ln & 15);
    const int k   = w * 32 + ((ln >> 4) << 3);
    f32x4 v[2];
    v[0] = *reinterpret_cast<const f32x4*>(gw + (long)row * 4096 + k);
    v[1] = *reinterpret_cast<const f32x4*>(gw + (long)row * 4096 + k + 4);
    short8 h, l;
    cvt8(v, &h, &l);
    bh[tid] = h;
    bl[tid] = l;
}

__device__ __forceinline__ void gload16(const void* g, void* l) {
    __builtin_amdgcn_global_load_lds(
        (const __attribute__((address_space(1))) void*)g,
        (__attribute__((address_space(3))) void*)l, 16, 0, 0);
}

// LDS per buffer (32KB): A [64 rows][256B] @0, B 16 segs of 1KB @16384.
// B seg s = wl*8 + nt*2 + hl (wl = local k-window 0..1).
// buf0 @0, buf1 @32768.
#define STAGE(C, BUF) do {                                                    \
    char* aB = AB + (BUF) * 32768;                                            \
    char* bB = aB + 16384;                                                    \
    _Pragma("unroll")                                                         \
    for (int i = 0; i < 4; ++i)                                               \
        gload16(srcA[i] + (long)(C) * 256, aB + (wv * 4 + i) * 1024 + ln * 16); \
    _Pragma("unroll")                                                         \
    for (int i = 0; i < 4; ++i) {                                             \
        const int s  = wv * 4 + i;                                            \
        const int wl = s >> 3, nt = (s >> 1) & 3, hl = s & 1;                 \
        const short8* sp = (hl ? blp : bhp)                                   \
            + ((long)nt * 8192 + (2 * (C) + wl) * 64 + ln);                   \
        gload16(sp, bB + s * 1024 + ln * 16);                                 \
    }                                                                         \
} while (0)

__global__ __launch_bounds__(256, 2)
void router_fused(const float* __restrict__ x,
                  const short8* __restrict__ bhp,
                  const short8* __restrict__ blp,
                  const float* __restrict__ gw,
                  float* __restrict__ out,
                  int M, int K) {
    __shared__ __align__(16) char AB[65536];
    __shared__ int flags[TPB];
    __shared__ double Ld4[4][64];

    const int t  = threadIdx.x;
    const int wv = t >> 6;                  // wave = m-tile (16 tokens)
    const int ln = t & 63;
    const int fr = ln & 15;
    const int q  = ln >> 4;
    const long tok0 = (long)blockIdx.x * TPB;
    const int phase = blockIdx.x & (NCH - 1);

    // A staging: instr jj=wv*4+i covers rows 4jj..4jj+3 (1KB contiguous LDS);
    // lane -> row 4jj+(ln>>4), physical slot ln&15; global slot pre-swizzled
    // (octet-local XOR with row&7) so swizzled reads see linear data.
    const char* srcA[4];
#pragma unroll
    for (int i = 0; i < 4; ++i) {
        const int row  = (wv * 4 + i) * 4 + (ln >> 4);
        const int sl   = ln & 15;
        const int lslot = (sl & 8) | ((sl & 7) ^ (row & 7));
        srcA[i] = (const char*)x + (tok0 + row) * (long)K * 4 + lslot * 16;
    }

    f32x4 acc[4];
#pragma unroll
    for (int nt = 0; nt < 4; ++nt) acc[nt] = (f32x4){0.f, 0.f, 0.f, 0.f};

    STAGE(phase, 0);
    STAGE((phase + 1) & (NCH - 1), 1);

    const int R  = wv * 16 + fr;            // A row this lane consumes
    const int rk = R & 7;                   // swizzle key

    for (int j = 0; j < NCH; ++j) {
        const int c   = (phase + j) & (NCH - 1);
        const int buf = j & 1;
        if (j + 1 < NCH) asm volatile("s_waitcnt vmcnt(8)" ::: "memory");
        else             asm volatile("s_waitcnt vmcnt(0)" ::: "memory");
        __builtin_amdgcn_s_barrier();
        asm volatile("" ::: "memory");
        __builtin_amdgcn_sched_barrier(0);

        // ---- compute chunk c: 2 windows of k=32, all 4 n-tiles ----
        {
            const char* aB = AB + buf * 32768 + R * 256;
            const char* bB = AB + buf * 32768 + 16384;
#pragma unroll
            for (int wl = 0; wl < 2; ++wl) {
                f32x4 av[2];
                av[0] = *(const f32x4*)(aB + (wl * 8 + ((q * 2 + 0) ^ rk)) * 16);
                av[1] = *(const f32x4*)(aB + (wl * 8 + ((q * 2 + 1) ^ rk)) * 16);
                short8 ah, al;
                cvt8(av, &ah, &al);
#pragma unroll
                for (int nt = 0; nt < 4; ++nt) {
                    short8 bhv = *(const short8*)(bB + (wl * 8 + nt * 2 + 0) * 1024 + ln * 16);
                    short8 blv = *(const short8*)(bB + (wl * 8 + nt * 2 + 1) * 1024 + ln * 16);
                    acc[nt] = __builtin_amdgcn_mfma_f32_16x16x32_bf16(ah, bhv, acc[nt], 0, 0, 0);
                    acc[nt] = __builtin_amdgcn_mfma_f32_16x16x32_bf16(ah, blv, acc[nt], 0, 0, 0);
                    acc[nt] = __builtin_amdgcn_mfma_f32_16x16x32_bf16(al, bhv, acc[nt], 0, 0, 0);
                    acc[nt] = __builtin_amdgcn_mfma_f32_16x16x32_bf16(al, blv, acc[nt], 0, 0, 0);
                }
            }
        }

        __builtin_amdgcn_sched_barrier(0);
        asm volatile("" ::: "memory");
        __builtin_amdgcn_s_barrier();       // all waves done reading buf
        asm volatile("" ::: "memory");
        if (j + 2 < NCH) STAGE((phase + j + 2) & (NCH - 1), buf);
        __builtin_amdgcn_sched_barrier(0);
    }

    // ---- epilogue: dump logits (C/D: col=lane&15, row=q*4+r) ----
    __syncthreads();
    float* Ls = (float*)AB;                 // 64*68*4 = 17.4KB, loop done
#pragma unroll
    for (int nt = 0; nt < 4; ++nt)
#pragma unroll
        for (int r = 0; r < 4; ++r)
            Ls[(wv * 16 + q * 4 + r) * LROW + nt * 16 + fr] = acc[nt][r];
    __syncthreads();

    if (t < TPB) {
        const float* row = Ls + (long)t * LROW;
        float m1 = -INFINITY, m2 = -INFINITY, m3 = -INFINITY;
        int i1 = 0, i2 = 0;
#pragma unroll 8
        for (int e = 0; e < 64; ++e) {
            const float v = row[e];
            if (v > m1)      { m3 = m2; m2 = m1; i2 = i1; m1 = v; i1 = e; }
            else if (v > m2) { m3 = m2; m2 = v; i2 = e; }
            else if (v > m3) { m3 = v; }
        }
        const float e2 = expf(m2 - m1);
        const float s  = 1.0f + e2;

        const long g = tok0 + t;
        out[2 * g + 0] = 1.0f / s;
        out[2 * g + 1] = e2 / s;
        float* oi = out + 2 * (long)M;
        oi[2 * g + 0] = (float)i1;
        oi[2 * g + 1] = (float)i2;

        flags[t] = ((m1 - m2) < TAU) | ((m2 - m3) < TAU);
    }
    __syncthreads();

    // ---- fp64 refine, 256 threads cooperate (wave=K-quarter, lane=expert) ----
    for (int tk = 0; tk < TPB; ++tk) {
        if (flags[tk]) {
            const float* xr = x + (tok0 + tk) * (long)K + wv * 1024;
            const float* gr = gw + (long)ln * (long)K + wv * 1024;
            double s0 = 0.0, s1 = 0.0, s2 = 0.0, s3 = 0.0;
            for (int k = 0; k < 1024; k += 4) {
                const f32x4 a = *reinterpret_cast<const f32x4*>(xr + k);
                const f32x4 b = *reinterpret_cast<const f32x4*>(gr + k);
                s0 = fma((double)a.x, (double)b.x, s0);
                s1 = fma((double)a.y, (double)b.y, s1);
                s2 = fma((double)a.z, (double)b.z, s2);
                s3 = fma((double)a.w, (double)b.w, s3);
            }
            Ld4[wv][ln] = (s0 + s1) + (s2 + s3);
            __syncthreads();
            if (t == 0) {
                double m1 = -INFINITY, m2 = -INFINITY;
                int i1 = 0, i2 = 0;
                for (int e = 0; e < 64; ++e) {
                    const double v = Ld4[0][e] + Ld4[1][e] + Ld4[2][e] + Ld4[3][e];
                    if (v > m1)      { m2 = m1; i2 = i1; m1 = v; i1 = e; }
                    else if (v > m2) { m2 = v; i2 = e; }
                }
                const double e2 = exp(m2 - m1);
                const double s  = 1.0 + e2;
                const long g = tok0 + tk;
                out[2 * g + 0] = (float)(1.0 / s);
                out[2 * g + 1] = (float)(e2 / s);
                float* oi = out + 2 * (long)M;
                oi[2 * g + 0] = (float)i1;
                oi[2 * g + 1] = (float)i2;
            }
            __syncthreads();
        }
    }
}

extern "C" void kernel_launch(void* const* d_in, const int* in_sizes, int n_in,
                              void* d_out, int out_size, void* d_ws, size_t ws_size,
                              hipStream_t stream) {
    const float* x  = (const float*)d_in[0];
    const float* gw = (const float*)d_in[1];
    float* out = (float*)d_out;

    const int K = 4096;
    const int M = in_sizes[0] / K;          // 32768 tokens
    const int nblocks = M / TPB;            // 512

    short8* bh = (short8*)d_ws;             // 1 MB packed B
    short8* bl = bh + 32768;

    prep_b<<<128, 256, 0, stream>>>(gw, bh, bl);
    router_fused<<<nblocks, 256, 0, stream>>>(x, bh, bl, gw, out, M, K);
}